// Round 1
// baseline (974.699 us; speedup 1.0000x reference)
//
#include <hip/hip_runtime.h>
#include <hip/hip_bf16.h>

// LBKT cell. Constants from reference.
#define NUx 128
#define MSx 64
#define IN_W 323
#define B_TOT 4096

__device__ __forceinline__ float sigmoidf_(float x) { return 1.0f / (1.0f + __expf(-x)); }
__device__ __forceinline__ float bf2f_(unsigned short u) {
    unsigned int x = ((unsigned int)u) << 16;
    return __uint_as_float(x);
}

// Block-cooperative GEMM: 8 batches x 128 outputs, K multiple of 32.
// Wave w handles b={2w,2w+1}; lane l handles n={l,l+64}. Weight tiles staged in LDS.
template <typename XF>
__device__ __forceinline__ void gemm_block(const float* __restrict__ W, int K,
                                           float (*s_wt)[128], int tid, int bA, int bB,
                                           int n0, int n1, XF xf,
                                           float& a00, float& a01, float& a10, float& a11) {
    for (int kb = 0; kb < K; kb += 32) {
        __syncthreads();  // previous users of s_wt done; also publishes X writes
        for (int i = tid; i < 32 * 128; i += 256) {
            int kk = i >> 7, nn = i & 127;
            s_wt[kk][nn] = W[(kb + kk) * 128 + nn];
        }
        __syncthreads();
#pragma unroll 8
        for (int k = 0; k < 32; ++k) {
            float w0 = s_wt[k][n0], w1 = s_wt[k][n1];
            float xA = xf(bA, kb + k), xB = xf(bB, kb + k);
            a00 += xA * w0; a01 += xA * w1;
            a10 += xB * w0; a11 += xB * w1;
        }
    }
}

// Kernel 1: per-batch stage. 8 batches/block.
// Computes h_pre_tilde, preds, gate gains, learning_gain, cvec (per-b part of forget-gate preact).
__global__ __launch_bounds__(256) void k1_kernel(
    const float* __restrict__ inp, const float* __restrict__ hp,
    const float* __restrict__ tw, const float* __restrict__ aw, const float* __restrict__ hw,
    const float* __restrict__ wf, const float* __restrict__ bias,
    const float* __restrict__ g3W, const float* __restrict__ g3b,
    const float* __restrict__ oW, const float* __restrict__ ob,
    const float* __restrict__ tgW, const float* __restrict__ tgb,
    const float* __restrict__ agW, const float* __restrict__ agb,
    const float* __restrict__ hgW, const float* __restrict__ hgb,
    float* __restrict__ ws_preds, float* __restrict__ ws_lg, float* __restrict__ ws_cvec) {
    __shared__ float s_ie[8][128], s_topic[8][128], s_hpt[8][128];
    __shared__ float s_corr[8][64], s_scal[8][4];
    __shared__ float s_gains[3][8][128];
    __shared__ float s_wt[32][128];
    __shared__ float s_wsum[3][128];

    const int tid = threadIdx.x;
    const int b0 = blockIdx.x * 8;
    const int wave = tid >> 6, lane = tid & 63;
    const int bA = 2 * wave, bB = 2 * wave + 1;
    const int n0 = lane, n1 = lane + 64;

    // P0: stage input fields
    for (int i = tid; i < 8 * IN_W; i += 256) {
        int bl = i / IN_W, j = i - bl * IN_W;
        float v = inp[(size_t)(b0 + bl) * IN_W + j];
        if (j < 128) s_ie[bl][j] = v;
        else if (j < 192) s_corr[bl][j - 128] = v;
        else if (j < 320) s_topic[bl][j - 192] = v;
        else s_scal[bl][j - 320] = v;
    }
    // row-sums of gate3_W for the tiled t/a/h scalar features
    if (tid < 128) {
        int n = tid;
        float st = 0.f, sa = 0.f, sh = 0.f;
        for (int k = 0; k < 50; ++k) {
            st += g3W[(256 + k) * 128 + n];
            sa += g3W[(306 + k) * 128 + n];
            sh += g3W[(356 + k) * 128 + n];
        }
        s_wsum[0][n] = st; s_wsum[1][n] = sa; s_wsum[2][n] = sh;
    }
    __syncthreads();

    // P1: h_pre_tilde[b][n] = sum_m corr[m]*h_pre[b][m][n]
    for (int j = 0; j < 4; ++j) {
        int idx = j * 256 + tid;
        int bl = idx >> 7, n = idx & 127;
        const float* hpb = hp + (size_t)(b0 + bl) * MSx * NUx + n;
        float acc = 0.f;
#pragma unroll 4
        for (int m = 0; m < 64; ++m) acc += s_corr[bl][m] * hpb[m * 128];
        s_hpt[bl][n] = acc;
    }
    // (gemm's internal sync publishes s_hpt)

    // P2: preds = mean_n sigmoid([hpt|topic] @ oW + ob)
    {
        float a00 = 0, a01 = 0, a10 = 0, a11 = 0;
        gemm_block(oW, 256, s_wt, tid, bA, bB, n0, n1,
                   [&](int b, int k) { return k < 128 ? s_hpt[b][k] : s_topic[b][k - 128]; },
                   a00, a01, a10, a11);
        float sA = sigmoidf_(a00 + ob[n0]) + sigmoidf_(a01 + ob[n1]);
        float sB = sigmoidf_(a10 + ob[n0]) + sigmoidf_(a11 + ob[n1]);
#pragma unroll
        for (int off = 32; off > 0; off >>= 1) {
            sA += __shfl_down(sA, off);
            sB += __shfl_down(sB, off);
        }
        if (lane == 0) {
            ws_preds[b0 + bA] = sA / 128.f;
            ws_preds[b0 + bB] = sB / 128.f;
        }
    }

    // P3: gate gains (time, attempt, hint)
    const float* GW[3] = {tgW, agW, hgW};
    const float* GB[3] = {tgb, agb, hgb};
    for (int g = 0; g < 3; ++g) {
        float z00 = 0, z01 = 0, z10 = 0, z11 = 0;
        gemm_block(GW[g], 256, s_wt, tid, bA, bB, n0, n1,
                   [&](int b, int k) { return k < 128 ? s_hpt[b][k] : s_ie[b][k - 128]; },
                   z00, z01, z10, z11);
        float gfA = 0.3f + 0.7f * sigmoidf_(10.f * (s_scal[bA][g] - 0.3f));
        float gfB = 0.3f + 0.7f * sigmoidf_(10.f * (s_scal[bB][g] - 0.3f));
        const float* gb = GB[g];
        s_gains[g][bA][n0] = sigmoidf_((z00 + gb[n0]) * gfA);
        s_gains[g][bA][n1] = sigmoidf_((z01 + gb[n1]) * gfA);
        s_gains[g][bB][n0] = sigmoidf_((z10 + gb[n0]) * gfB);
        s_gains[g][bB][n1] = sigmoidf_((z11 + gb[n1]) * gfB);
    }

    // P4: fusion + learning gain
    {
        float l00 = 0, l01 = 0, l10 = 0, l11 = 0;
        const float* FW[3] = {tw, aw, hw};
        for (int r = 0; r < 4; ++r) {
            float p00 = 1.f, p01 = 1.f, p10 = 1.f, p11 = 1.f;
            for (int g = 0; g < 3; ++g) {
                float f00 = 0, f01 = 0, f10 = 0, f11 = 0;
                const float* Wg = FW[g] + (size_t)r * 129 * 128;
                gemm_block(Wg, 128, s_wt, tid, bA, bB, n0, n1,
                           [&](int b, int k) { return s_gains[g][b][k]; },
                           f00, f01, f10, f11);
                const float* pr = Wg + 128 * 128;  // pad row (u=128, x=1)
                f00 += pr[n0]; f01 += pr[n1]; f10 += pr[n0]; f11 += pr[n1];
                p00 *= f00; p01 *= f01; p10 *= f10; p11 *= f11;
            }
            float w = wf[r];
            l00 += w * p00; l01 += w * p01; l10 += w * p10; l11 += w * p11;
        }
        l00 = fmaxf(l00 + bias[n0], 0.f);
        l01 = fmaxf(l01 + bias[n1], 0.f);
        l10 = fmaxf(l10 + bias[n0], 0.f);
        l11 = fmaxf(l11 + bias[n1], 0.f);
        ws_lg[(size_t)(b0 + bA) * 128 + n0] = l00;
        ws_lg[(size_t)(b0 + bA) * 128 + n1] = l01;
        ws_lg[(size_t)(b0 + bB) * 128 + n0] = l10;
        ws_lg[(size_t)(b0 + bB) * 128 + n1] = l11;
    }

    // P5: cvec = ie @ W2 + t*wsum_t + a*wsum_a + h*wsum_h + g3b
    {
        float c00 = 0, c01 = 0, c10 = 0, c11 = 0;
        gemm_block(g3W + 128 * 128, 128, s_wt, tid, bA, bB, n0, n1,
                   [&](int b, int k) { return s_ie[b][k]; },
                   c00, c01, c10, c11);
        float tA = s_scal[bA][0], aA = s_scal[bA][1], hA = s_scal[bA][2];
        float tB = s_scal[bB][0], aB = s_scal[bB][1], hB = s_scal[bB][2];
        c00 += tA * s_wsum[0][n0] + aA * s_wsum[1][n0] + hA * s_wsum[2][n0] + g3b[n0];
        c01 += tA * s_wsum[0][n1] + aA * s_wsum[1][n1] + hA * s_wsum[2][n1] + g3b[n1];
        c10 += tB * s_wsum[0][n0] + aB * s_wsum[1][n0] + hB * s_wsum[2][n0] + g3b[n0];
        c11 += tB * s_wsum[0][n1] + aB * s_wsum[1][n1] + hB * s_wsum[2][n1] + g3b[n1];
        ws_cvec[(size_t)(b0 + bA) * 128 + n0] = c00;
        ws_cvec[(size_t)(b0 + bA) * 128 + n1] = c01;
        ws_cvec[(size_t)(b0 + bB) * 128 + n0] = c10;
        ws_cvec[(size_t)(b0 + bB) * 128 + n1] = c11;
    }
}

// Kernel 2: forget gate GEMM (h_pre @ W1) + h epilogue + h_tilde partial. One batch per block.
__global__ __launch_bounds__(256) void k2_kernel(
    const float* __restrict__ hp, const float* __restrict__ inp,
    const float* __restrict__ g3W,
    const float* __restrict__ ws_lg, const float* __restrict__ ws_cvec,
    float* __restrict__ out_h, float* __restrict__ ws_htld) {
    __shared__ float s_hp[64][129];             // +1 pad: conflict-free column reads
    __shared__ __hip_bfloat16 s_w1[128][128];   // W1 in bf16 to fit 2 blocks/CU
    __shared__ float s_corr[64], s_lg[128], s_cv[128];
    __shared__ float s_htp[16][132];

    const int tid = threadIdx.x;
    const int b = blockIdx.x;

    const float* hpb = hp + (size_t)b * MSx * NUx;
    for (int i4 = tid; i4 < 2048; i4 += 256) {
        float4 v = *(const float4*)(hpb + i4 * 4);
        int row = i4 >> 5, col = (i4 & 31) * 4;
        s_hp[row][col] = v.x; s_hp[row][col + 1] = v.y;
        s_hp[row][col + 2] = v.z; s_hp[row][col + 3] = v.w;
    }
    for (int i4 = tid; i4 < 4096; i4 += 256) {
        float4 v = *(const float4*)(g3W + i4 * 4);
        int row = i4 >> 5, col = (i4 & 31) * 4;
        s_w1[row][col] = __float2bfloat16(v.x);
        s_w1[row][col + 1] = __float2bfloat16(v.y);
        s_w1[row][col + 2] = __float2bfloat16(v.z);
        s_w1[row][col + 3] = __float2bfloat16(v.w);
    }
    if (tid < 64) s_corr[tid] = inp[(size_t)b * IN_W + 128 + tid];
    if (tid < 128) {
        s_lg[tid] = ws_lg[(size_t)b * 128 + tid];
        s_cv[tid] = ws_cvec[(size_t)b * 128 + tid];
    }
    __syncthreads();

    const int tr = tid >> 4, tc = tid & 15;
    const int r0 = tr * 4;
    const int cA = tc * 4, cB = 64 + tc * 4;

    float acc[4][8];
#pragma unroll
    for (int r = 0; r < 4; ++r)
#pragma unroll
        for (int j = 0; j < 8; ++j) acc[r][j] = 0.f;

#pragma unroll 2
    for (int k = 0; k < 128; ++k) {
        float a_[4];
#pragma unroll
        for (int r = 0; r < 4; ++r) a_[r] = s_hp[r0 + r][k];
        ushort4 wa = *(const ushort4*)&s_w1[k][cA];
        ushort4 wb = *(const ushort4*)&s_w1[k][cB];
        float wA0 = bf2f_(wa.x), wA1 = bf2f_(wa.y), wA2 = bf2f_(wa.z), wA3 = bf2f_(wa.w);
        float wB0 = bf2f_(wb.x), wB1 = bf2f_(wb.y), wB2 = bf2f_(wb.z), wB3 = bf2f_(wb.w);
#pragma unroll
        for (int r = 0; r < 4; ++r) {
            acc[r][0] += a_[r] * wA0; acc[r][1] += a_[r] * wA1;
            acc[r][2] += a_[r] * wA2; acc[r][3] += a_[r] * wA3;
            acc[r][4] += a_[r] * wB0; acc[r][5] += a_[r] * wB1;
            acc[r][6] += a_[r] * wB2; acc[r][7] += a_[r] * wB3;
        }
    }

    float hpart[8];
#pragma unroll
    for (int j = 0; j < 8; ++j) hpart[j] = 0.f;
    float* outb = out_h + (size_t)b * MSx * NUx;
#pragma unroll
    for (int r = 0; r < 4; ++r) {
        int row = r0 + r;
        float cr = s_corr[row];
        float4 o0, o1;
        float* po0 = (float*)&o0;
        float* po1 = (float*)&o1;
#pragma unroll
        for (int j = 0; j < 4; ++j) {
            int col = cA + j;
            float fg = sigmoidf_(acc[r][j] + s_cv[col]);
            float hval = s_hp[row][col] * fg + cr * s_lg[col];
            po0[j] = hval;
            hpart[j] += cr * hval;
        }
#pragma unroll
        for (int j = 0; j < 4; ++j) {
            int col = cB + j;
            float fg = sigmoidf_(acc[r][4 + j] + s_cv[col]);
            float hval = s_hp[row][col] * fg + cr * s_lg[col];
            po1[j] = hval;
            hpart[4 + j] += cr * hval;
        }
        *(float4*)(outb + row * 128 + cA) = o0;
        *(float4*)(outb + row * 128 + cB) = o1;
    }
#pragma unroll
    for (int j = 0; j < 4; ++j) {
        s_htp[tr][cA + j] = hpart[j];
        s_htp[tr][cB + j] = hpart[4 + j];
    }
    __syncthreads();
    if (tid < 128) {
        float s = 0.f;
#pragma unroll
        for (int t = 0; t < 16; ++t) s += s_htp[t][tid];
        ws_htld[(size_t)b * 128 + tid] = s;
    }
}

// Kernel 3: after_preds + improve + result. 8 batches/block.
__global__ __launch_bounds__(256) void k3_kernel(
    const float* __restrict__ inp, const float* __restrict__ ws_htld,
    const float* __restrict__ ws_preds,
    const float* __restrict__ oW, const float* __restrict__ ob,
    float* __restrict__ out_res) {
    __shared__ float s_htl[8][128], s_topic[8][128];
    __shared__ float s_wt[32][128];

    const int tid = threadIdx.x;
    const int b0 = blockIdx.x * 8;
    const int wave = tid >> 6, lane = tid & 63;
    const int bA = 2 * wave, bB = 2 * wave + 1;
    const int n0 = lane, n1 = lane + 64;

    for (int i = tid; i < 1024; i += 256) {
        int bl = i >> 7, n = i & 127;
        s_htl[bl][n] = ws_htld[(size_t)(b0 + bl) * 128 + n];
        s_topic[bl][n] = inp[(size_t)(b0 + bl) * IN_W + 192 + n];
    }

    float a00 = 0, a01 = 0, a10 = 0, a11 = 0;
    gemm_block(oW, 256, s_wt, tid, bA, bB, n0, n1,
               [&](int b, int k) { return k < 128 ? s_htl[b][k] : s_topic[b][k - 128]; },
               a00, a01, a10, a11);
    float sA = sigmoidf_(a00 + ob[n0]) + sigmoidf_(a01 + ob[n1]);
    float sB = sigmoidf_(a10 + ob[n0]) + sigmoidf_(a11 + ob[n1]);
#pragma unroll
    for (int off = 32; off > 0; off >>= 1) {
        sA += __shfl_down(sA, off);
        sB += __shfl_down(sB, off);
    }
    if (lane == 0) {
        float pA = ws_preds[b0 + bA];
        float pB = ws_preds[b0 + bB];
        float apA = sA / 128.f, apB = sB / 128.f;
        out_res[(size_t)(b0 + bA) * 2 + 0] = pA;
        out_res[(size_t)(b0 + bA) * 2 + 1] = (apA - pA) / (1.f - pA);
        out_res[(size_t)(b0 + bB) * 2 + 0] = pB;
        out_res[(size_t)(b0 + bB) * 2 + 1] = (apB - pB) / (1.f - pB);
    }
}

extern "C" void kernel_launch(void* const* d_in, const int* in_sizes, int n_in,
                              void* d_out, int out_size, void* d_ws, size_t ws_size,
                              hipStream_t stream) {
    const float* inp  = (const float*)d_in[0];
    const float* st   = (const float*)d_in[1];
    const float* tw   = (const float*)d_in[2];
    const float* aw   = (const float*)d_in[3];
    const float* hw   = (const float*)d_in[4];
    const float* wf   = (const float*)d_in[5];
    const float* bias = (const float*)d_in[6];
    const float* g3W  = (const float*)d_in[7];
    const float* g3b  = (const float*)d_in[8];
    const float* oW   = (const float*)d_in[9];
    const float* ob   = (const float*)d_in[10];
    const float* tgW  = (const float*)d_in[11];
    const float* tgb  = (const float*)d_in[12];
    const float* agW  = (const float*)d_in[13];
    const float* agb  = (const float*)d_in[14];
    const float* hgW  = (const float*)d_in[15];
    const float* hgb  = (const float*)d_in[16];

    float* out = (float*)d_out;
    float* out_res = out;            // (4096, 2)
    float* out_h = out + 2 * B_TOT;  // (4096, 64, 128)

    float* wsf = (float*)d_ws;
    float* ws_preds = wsf;                       // 4096
    float* ws_lg    = wsf + B_TOT;               // 4096*128
    float* ws_cvec  = ws_lg + (size_t)B_TOT * 128;
    float* ws_htld  = ws_cvec + (size_t)B_TOT * 128;

    k1_kernel<<<B_TOT / 8, 256, 0, stream>>>(inp, st, tw, aw, hw, wf, bias, g3W, g3b,
                                             oW, ob, tgW, tgb, agW, agb, hgW, hgb,
                                             ws_preds, ws_lg, ws_cvec);
    k2_kernel<<<B_TOT, 256, 0, stream>>>(st, inp, g3W, ws_lg, ws_cvec, out_h, ws_htld);
    k3_kernel<<<B_TOT / 8, 256, 0, stream>>>(inp, ws_htld, ws_preds, oW, ob, out_res);
}

// Round 2
// 356.075 us; speedup vs baseline: 2.7373x; 2.7373x over previous
//
#include <hip/hip_runtime.h>

#define B_TOT 4096
#define IN_W 323

typedef __attribute__((ext_vector_type(8))) short short8;
typedef __attribute__((ext_vector_type(4))) float f32x4;
typedef unsigned short ushort_t;

#define MFMA16(a, b, c) __builtin_amdgcn_mfma_f32_16x16x32_bf16(a, b, c, 0, 0, 0)

__device__ __forceinline__ float sigmoidf_(float x) { return 1.0f / (1.0f + __expf(-x)); }

__device__ __forceinline__ ushort_t f2bf(float f) {
    unsigned int u = __float_as_uint(f);
    u += 0x7FFF + ((u >> 16) & 1);
    return (ushort_t)(u >> 16);
}

union BF8 { ushort_t u[8]; short8 v; };

struct WS {
    ushort_t *hpt, *ieb, *topb, *gains, *htldb;
    ushort_t *oWb, *tgWb, *agWb, *hgWb, *g3W2b, *W1b, *fWb;
    float *wsum, *preds, *cvec, *lg;
};

// ---------------- k0: prep (weight transposes to k-major bf16, activation bf16, wsum) ----
__global__ __launch_bounds__(256) void k0_prep(
    const float* __restrict__ inp, const float* __restrict__ oW,
    const float* __restrict__ tgW, const float* __restrict__ agW, const float* __restrict__ hgW,
    const float* __restrict__ g3W, const float* __restrict__ tw, const float* __restrict__ aw,
    const float* __restrict__ hw, WS w) {
    int bx = blockIdx.x, tid = threadIdx.x;
    if (bx < 128) {  // K=256 matrices: oW, tgW, agW, hgW
        int mat = bx >> 5, c = bx & 31;
        const float* src = mat == 0 ? oW : mat == 1 ? tgW : mat == 2 ? agW : hgW;
        ushort_t* dst = mat == 0 ? w.oWb : mat == 1 ? w.tgWb : mat == 2 ? w.agWb : w.hgWb;
        if (tid < 128) {
            int n = tid;
#pragma unroll
            for (int j = 0; j < 8; ++j)
                dst[(size_t)n * 256 + c * 8 + j] = f2bf(src[(size_t)(c * 8 + j) * 128 + n]);
        }
    } else if (bx < 352) {  // K=128 matrices: g3W2, W1, 12 fusion
        int i = bx - 128, mat = i >> 4, c = i & 15;
        const float* src;
        ushort_t* dst;
        if (mat == 0) { src = g3W + 128 * 128; dst = w.g3W2b; }
        else if (mat == 1) { src = g3W; dst = w.W1b; }
        else {
            int f = mat - 2, g = f >> 2, r = f & 3;
            const float* base = g == 0 ? tw : g == 1 ? aw : hw;
            src = base + (size_t)r * 129 * 128;
            dst = w.fWb + (size_t)f * 128 * 128;
        }
        if (tid < 128) {
            int n = tid;
#pragma unroll
            for (int j = 0; j < 8; ++j)
                dst[(size_t)n * 128 + c * 8 + j] = f2bf(src[(size_t)(c * 8 + j) * 128 + n]);
        }
    } else if (bx == 352) {  // wsum rows of gate3_W for tiled scalars
        if (tid < 128) {
            int n = tid;
            float st = 0.f, sa = 0.f, sh = 0.f;
            for (int k = 0; k < 50; ++k) {
                st += g3W[(size_t)(256 + k) * 128 + n];
                sa += g3W[(size_t)(306 + k) * 128 + n];
                sh += g3W[(size_t)(356 + k) * 128 + n];
            }
            w.wsum[n] = st; w.wsum[128 + n] = sa; w.wsum[256 + n] = sh;
        }
    } else {  // activations: ie_b, topic_b
        int id0 = (bx - 353) * 256 + tid;
        for (int id = id0; id < 2 * B_TOT * 128; id += 1024 * 256) {
            int arr = id >> 19;
            int rem = id & 524287;
            int b = rem >> 7, n = rem & 127;
            float v = inp[(size_t)b * IN_W + (arr ? 192 : 0) + n];
            (arr ? w.topb : w.ieb)[rem] = f2bf(v);
        }
    }
}

// ---------------- k1a: h_pre_tilde = corr @ h_pre (memory-bound) --------------------------
__global__ __launch_bounds__(256) void k1a_hpt(const float* __restrict__ inp,
                                               const float* __restrict__ hp, WS w) {
    __shared__ float s_corr[8][64];
    int tid = threadIdx.x, b0 = blockIdx.x * 8;
    for (int i = tid; i < 512; i += 256) {
        int bl = i >> 6, m = i & 63;
        s_corr[bl][m] = inp[(size_t)(b0 + bl) * IN_W + 128 + m];
    }
    __syncthreads();
    int bl = tid >> 5, c4 = (tid & 31) * 4;
    const float* hpb = hp + (size_t)(b0 + bl) * 8192 + c4;
    float a0 = 0, a1 = 0, a2 = 0, a3 = 0;
#pragma unroll 8
    for (int m = 0; m < 64; ++m) {
        float cr = s_corr[bl][m];
        float4 v = *(const float4*)(hpb + m * 128);
        a0 += cr * v.x; a1 += cr * v.y; a2 += cr * v.z; a3 += cr * v.w;
    }
    ushort_t* dst = w.hpt + (size_t)(b0 + bl) * 128 + c4;
    dst[0] = f2bf(a0); dst[1] = f2bf(a1); dst[2] = f2bf(a2); dst[3] = f2bf(a3);
}

// ---------------- k1b: 5 GEMM jobs: preds / 3 gates / cvec -------------------------------
__global__ __launch_bounds__(256) void k1b_gemms(
    const float* __restrict__ inp, const float* __restrict__ ob,
    const float* __restrict__ tgb, const float* __restrict__ agb, const float* __restrict__ hgb,
    const float* __restrict__ g3b, WS w) {
    __shared__ float s_red[4][16];
    int tid = threadIdx.x;
    int job = blockIdx.y;
    int m0 = blockIdx.x * 16;
    int wv = tid >> 6, l = tid & 63;
    int lr = l & 15, lg_ = l >> 4;
    int ncol0 = wv * 32;
    const ushort_t* Bw = job == 0 ? w.oWb : job == 1 ? w.tgWb : job == 2 ? w.agWb
                         : job == 3 ? w.hgWb : w.g3W2b;
    const int K = (job == 4) ? 128 : 256;
    f32x4 acc0 = {0, 0, 0, 0}, acc1 = {0, 0, 0, 0};
    for (int k0 = 0; k0 < K; k0 += 32) {
        const ushort_t* Ab;
        int ka;
        if (job == 4) { Ab = w.ieb; ka = k0; }
        else if (k0 < 128) { Ab = w.hpt; ka = k0; }
        else { Ab = (job == 0) ? w.topb : w.ieb; ka = k0 - 128; }
        short8 a = *(const short8*)(Ab + (size_t)(m0 + lr) * 128 + ka + lg_ * 8);
        short8 b0v = *(const short8*)(Bw + (size_t)(ncol0 + lr) * K + k0 + lg_ * 8);
        short8 b1v = *(const short8*)(Bw + (size_t)(ncol0 + 16 + lr) * K + k0 + lg_ * 8);
        acc0 = MFMA16(a, b0v, acc0);
        acc1 = MFMA16(a, b1v, acc1);
    }
    if (job == 0) {
        float s[4];
#pragma unroll
        for (int rr = 0; rr < 4; ++rr)
            s[rr] = sigmoidf_(acc0[rr] + ob[ncol0 + lr]) + sigmoidf_(acc1[rr] + ob[ncol0 + 16 + lr]);
#pragma unroll
        for (int off = 1; off <= 8; off <<= 1)
#pragma unroll
            for (int rr = 0; rr < 4; ++rr) s[rr] += __shfl_xor(s[rr], off);
        if (lr == 0)
#pragma unroll
            for (int rr = 0; rr < 4; ++rr) s_red[wv][lg_ * 4 + rr] = s[rr];
        __syncthreads();
        if (tid < 16) {
            float p = (s_red[0][tid] + s_red[1][tid] + s_red[2][tid] + s_red[3][tid]) * (1.f / 128.f);
            w.preds[m0 + tid] = p;
        }
    } else if (job <= 3) {
        const float* gb = job == 1 ? tgb : job == 2 ? agb : hgb;
        ushort_t* gout = w.gains + (size_t)(job - 1) * B_TOT * 128;
#pragma unroll
        for (int half = 0; half < 2; ++half) {
            f32x4 acc = half ? acc1 : acc0;
            int n = ncol0 + half * 16 + lr;
            float gbn = gb[n];
#pragma unroll
            for (int rr = 0; rr < 4; ++rr) {
                int b = m0 + lg_ * 4 + rr;
                float f = inp[(size_t)b * IN_W + 320 + (job - 1)];
                float gf = 0.3f + 0.7f * sigmoidf_(10.f * (f - 0.3f));
                gout[(size_t)b * 128 + n] = f2bf(sigmoidf_((acc[rr] + gbn) * gf));
            }
        }
    } else {
#pragma unroll
        for (int half = 0; half < 2; ++half) {
            f32x4 acc = half ? acc1 : acc0;
            int n = ncol0 + half * 16 + lr;
            float wst = w.wsum[n], wsa = w.wsum[128 + n], wsh = w.wsum[256 + n];
            float gbn = g3b[n];
#pragma unroll
            for (int rr = 0; rr < 4; ++rr) {
                int b = m0 + lg_ * 4 + rr;
                const float* sp = inp + (size_t)b * IN_W + 320;
                w.cvec[(size_t)b * 128 + n] = acc[rr] + sp[0] * wst + sp[1] * wsa + sp[2] * wsh + gbn;
            }
        }
    }
}

// ---------------- k1c: 12 fusion GEMMs + product + relu -> lg ----------------------------
__global__ __launch_bounds__(512) void k1c_fusion(
    const float* __restrict__ tw, const float* __restrict__ aw, const float* __restrict__ hw,
    const float* __restrict__ wf, const float* __restrict__ bias, WS w) {
    __shared__ float s_red[4][16][128];
    int tid = threadIdx.x;
    int m0 = blockIdx.x * 16;
    int wv = tid >> 6, l = tid & 63;
    int r = wv >> 1, nh = wv & 1;
    int lr = l & 15, lg_ = l >> 4;
    f32x4 acc[3][4];
#pragma unroll
    for (int g = 0; g < 3; ++g)
#pragma unroll
        for (int nt = 0; nt < 4; ++nt) acc[g][nt] = (f32x4){0, 0, 0, 0};
#pragma unroll
    for (int g = 0; g < 3; ++g) {
        const ushort_t* Ag = w.gains + (size_t)g * B_TOT * 128;
        const ushort_t* Bg = w.fWb + (size_t)(g * 4 + r) * 128 * 128;
#pragma unroll
        for (int k0 = 0; k0 < 128; k0 += 32) {
            short8 a = *(const short8*)(Ag + (size_t)(m0 + lr) * 128 + k0 + lg_ * 8);
#pragma unroll
            for (int nt = 0; nt < 4; ++nt) {
                short8 b = *(const short8*)(Bg + (size_t)(nh * 64 + nt * 16 + lr) * 128 + k0 + lg_ * 8);
                acc[g][nt] = MFMA16(a, b, acc[g][nt]);
            }
        }
    }
    float wfr = wf[r];
    const float* pad0 = tw + (size_t)(r * 129 + 128) * 128;
    const float* pad1 = aw + (size_t)(r * 129 + 128) * 128;
    const float* pad2 = hw + (size_t)(r * 129 + 128) * 128;
#pragma unroll
    for (int nt = 0; nt < 4; ++nt) {
        int n = nh * 64 + nt * 16 + lr;
        float p0 = pad0[n], p1 = pad1[n], p2 = pad2[n];
#pragma unroll
        for (int rr = 0; rr < 4; ++rr) {
            float F0 = acc[0][nt][rr] + p0;
            float F1 = acc[1][nt][rr] + p1;
            float F2 = acc[2][nt][rr] + p2;
            s_red[r][lg_ * 4 + rr][n] = wfr * F0 * F1 * F2;
        }
    }
    __syncthreads();
    for (int i = tid; i < 2048; i += 512) {
        int row = i >> 7, col = i & 127;
        float v = s_red[0][row][col] + s_red[1][row][col] + s_red[2][row][col] + s_red[3][row][col];
        w.lg[(size_t)(m0 + row) * 128 + col] = fmaxf(v + bias[col], 0.f);
    }
}

// ---------------- k2: forget-gate MFMA GEMM + h epilogue + h_tilde -----------------------
__global__ __launch_bounds__(256) void k2_big(const float* __restrict__ inp,
                                              const float* __restrict__ hp, WS w,
                                              float* __restrict__ out_h) {
    __shared__ __align__(16) ushort_t s_w1[128 * 136];
    __shared__ float s_corr[64], s_lg[128], s_cv[128], s_ht[4][128];
    int tid = threadIdx.x, b = blockIdx.x;
    for (int i = tid; i < 128 * 16; i += 256) {
        int row = i >> 4, c8 = (i & 15) * 8;
        *(short8*)(s_w1 + row * 136 + c8) = *(const short8*)(w.W1b + (size_t)row * 128 + c8);
    }
    if (tid < 64) s_corr[tid] = inp[(size_t)b * IN_W + 128 + tid];
    if (tid < 128) s_lg[tid] = w.lg[(size_t)b * 128 + tid];
    else if (tid < 256) { int t = tid - 128; s_cv[t] = w.cvec[(size_t)b * 128 + t]; }
    __syncthreads();
    int wv = tid >> 6, l = tid & 63;
    int lr = l & 15, lg_ = l >> 4;
    int m0 = wv * 16;
    const float* hpb = hp + (size_t)b * 8192;
    short8 afr[4];
#pragma unroll
    for (int k0i = 0; k0i < 4; ++k0i) {
        const float* p = hpb + (m0 + lr) * 128 + k0i * 32 + lg_ * 8;
        float4 x0 = *(const float4*)p, x1 = *(const float4*)(p + 4);
        BF8 t;
        t.u[0] = f2bf(x0.x); t.u[1] = f2bf(x0.y); t.u[2] = f2bf(x0.z); t.u[3] = f2bf(x0.w);
        t.u[4] = f2bf(x1.x); t.u[5] = f2bf(x1.y); t.u[6] = f2bf(x1.z); t.u[7] = f2bf(x1.w);
        afr[k0i] = t.v;
    }
    float* outb = out_h + (size_t)b * 8192;
#pragma unroll
    for (int nt = 0; nt < 8; ++nt) {
        f32x4 acc = {0, 0, 0, 0};
#pragma unroll
        for (int k0i = 0; k0i < 4; ++k0i) {
            short8 bv = *(const short8*)(s_w1 + (nt * 16 + lr) * 136 + k0i * 32 + lg_ * 8);
            acc = MFMA16(afr[k0i], bv, acc);
        }
        int n = nt * 16 + lr;
        float cv = s_cv[n], lgv = s_lg[n];
        float csum = 0.f;
#pragma unroll
        for (int rr = 0; rr < 4; ++rr) {
            int m = m0 + lg_ * 4 + rr;
            float fg = sigmoidf_(acc[rr] + cv);
            float hpv = hpb[m * 128 + n];
            float cr = s_corr[m];
            float hv = hpv * fg + cr * lgv;
            outb[m * 128 + n] = hv;
            csum += cr * hv;
        }
        csum += __shfl_xor(csum, 16);
        csum += __shfl_xor(csum, 32);
        if (l < 16) s_ht[wv][n] = csum;
    }
    __syncthreads();
    if (tid < 128) {
        float s = s_ht[0][tid] + s_ht[1][tid] + s_ht[2][tid] + s_ht[3][tid];
        w.htldb[(size_t)b * 128 + tid] = f2bf(s);
    }
}

// ---------------- k3: after_preds + improve ----------------------------------------------
__global__ __launch_bounds__(256) void k3_after(const float* __restrict__ ob, WS w,
                                               float* __restrict__ out_res) {
    __shared__ float s_red[4][16];
    int tid = threadIdx.x, m0 = blockIdx.x * 16;
    int wv = tid >> 6, l = tid & 63, lr = l & 15, lg_ = l >> 4;
    int ncol0 = wv * 32;
    f32x4 acc0 = {0, 0, 0, 0}, acc1 = {0, 0, 0, 0};
    for (int k0 = 0; k0 < 256; k0 += 32) {
        const ushort_t* Ab = (k0 < 128) ? w.htldb : w.topb;
        int ka = k0 & 127;
        short8 a = *(const short8*)(Ab + (size_t)(m0 + lr) * 128 + ka + lg_ * 8);
        short8 b0v = *(const short8*)(w.oWb + (size_t)(ncol0 + lr) * 256 + k0 + lg_ * 8);
        short8 b1v = *(const short8*)(w.oWb + (size_t)(ncol0 + 16 + lr) * 256 + k0 + lg_ * 8);
        acc0 = MFMA16(a, b0v, acc0);
        acc1 = MFMA16(a, b1v, acc1);
    }
    float s[4];
#pragma unroll
    for (int rr = 0; rr < 4; ++rr)
        s[rr] = sigmoidf_(acc0[rr] + ob[ncol0 + lr]) + sigmoidf_(acc1[rr] + ob[ncol0 + 16 + lr]);
#pragma unroll
    for (int off = 1; off <= 8; off <<= 1)
#pragma unroll
        for (int rr = 0; rr < 4; ++rr) s[rr] += __shfl_xor(s[rr], off);
    if (lr == 0)
#pragma unroll
        for (int rr = 0; rr < 4; ++rr) s_red[wv][lg_ * 4 + rr] = s[rr];
    __syncthreads();
    if (tid < 16) {
        float ap = (s_red[0][tid] + s_red[1][tid] + s_red[2][tid] + s_red[3][tid]) * (1.f / 128.f);
        float p = w.preds[m0 + tid];
        out_res[(size_t)(m0 + tid) * 2] = p;
        out_res[(size_t)(m0 + tid) * 2 + 1] = (ap - p) / (1.f - p);
    }
}

extern "C" void kernel_launch(void* const* d_in, const int* in_sizes, int n_in,
                              void* d_out, int out_size, void* d_ws, size_t ws_size,
                              hipStream_t stream) {
    const float* inp  = (const float*)d_in[0];
    const float* st   = (const float*)d_in[1];
    const float* tw   = (const float*)d_in[2];
    const float* aw   = (const float*)d_in[3];
    const float* hw   = (const float*)d_in[4];
    const float* wf   = (const float*)d_in[5];
    const float* bias = (const float*)d_in[6];
    const float* g3W  = (const float*)d_in[7];
    const float* g3b  = (const float*)d_in[8];
    const float* oW   = (const float*)d_in[9];
    const float* ob   = (const float*)d_in[10];
    const float* tgW  = (const float*)d_in[11];
    const float* tgb  = (const float*)d_in[12];
    const float* agW  = (const float*)d_in[13];
    const float* agb  = (const float*)d_in[14];
    const float* hgW  = (const float*)d_in[15];
    const float* hgb  = (const float*)d_in[16];

    float* out_res = (float*)d_out;                  // (4096, 2)
    float* out_h   = (float*)d_out + 2 * B_TOT;      // (4096, 64, 128)

    char* p = (char*)d_ws;
    auto alloc = [&](size_t bytes) { char* r = p; p += (bytes + 255) & ~255ull; return r; };
    WS w;
    w.hpt   = (ushort_t*)alloc((size_t)B_TOT * 128 * 2);
    w.ieb   = (ushort_t*)alloc((size_t)B_TOT * 128 * 2);
    w.topb  = (ushort_t*)alloc((size_t)B_TOT * 128 * 2);
    w.gains = (ushort_t*)alloc((size_t)3 * B_TOT * 128 * 2);
    w.htldb = (ushort_t*)alloc((size_t)B_TOT * 128 * 2);
    w.oWb   = (ushort_t*)alloc(256 * 128 * 2);
    w.tgWb  = (ushort_t*)alloc(256 * 128 * 2);
    w.agWb  = (ushort_t*)alloc(256 * 128 * 2);
    w.hgWb  = (ushort_t*)alloc(256 * 128 * 2);
    w.g3W2b = (ushort_t*)alloc(128 * 128 * 2);
    w.W1b   = (ushort_t*)alloc(128 * 128 * 2);
    w.fWb   = (ushort_t*)alloc(12 * 128 * 128 * 2);
    w.wsum  = (float*)alloc(3 * 128 * 4);
    w.preds = (float*)alloc(B_TOT * 4);
    w.cvec  = (float*)alloc((size_t)B_TOT * 128 * 4);
    w.lg    = (float*)alloc((size_t)B_TOT * 128 * 4);

    k0_prep<<<1377, 256, 0, stream>>>(inp, oW, tgW, agW, hgW, g3W, tw, aw, hw, w);
    k1a_hpt<<<B_TOT / 8, 256, 0, stream>>>(inp, st, w);
    k1b_gemms<<<dim3(B_TOT / 16, 5), 256, 0, stream>>>(inp, ob, tgb, agb, hgb, g3b, w);
    k1c_fusion<<<B_TOT / 16, 512, 0, stream>>>(tw, aw, hw, wf, bias, w);
    k2_big<<<B_TOT, 256, 0, stream>>>(inp, st, w, out_h);
    k3_after<<<B_TOT / 16, 256, 0, stream>>>(ob, w, out_res);
}